// Round 1
// baseline (1326.685 us; speedup 1.0000x reference)
//
#include <hip/hip_runtime.h>
#include <hip/hip_bf16.h>
#include <math.h>

#define NN 60000
#define NE 200000
#define DD 128
#define NH 4
#define HC 512   // NH * C
#define NL 3
#define VAv 128
#define VBv 16
#define SCAN_CHUNK 512

__device__ __forceinline__ float bf2f(unsigned short u){
    union{unsigned int i; float f;} v; v.i = ((unsigned int)u)<<16; return v.f;
}
__device__ __forceinline__ unsigned short f2bf(float f){
    union{float f; unsigned int i;} v; v.f = f;
    unsigned int r = v.i + 0x7fffu + ((v.i>>16)&1u);
    return (unsigned short)(r>>16);
}
__device__ __forceinline__ float lrelu(float v){ return v > 0.f ? v : 0.2f*v; }

// ---------------- embedding gather: h[n,:] = atom_emb[x[n],:] ----------------
__global__ void k_embed(const int* __restrict__ x, const float* __restrict__ atom_emb,
                        float* __restrict__ h) {
    int idx = blockIdx.x*blockDim.x + threadIdx.x;   // float4 index
    if (idx >= NN*(DD/4)) return;
    int n = idx >> 5;          // DD/4 == 32
    int c4 = idx & 31;
    int a = x[n];
    float4 v = ((const float4*)(atom_emb + (size_t)a*DD))[c4];
    ((float4*)(h + (size_t)n*DD))[c4] = v;
}

// ---------------- CSR build ----------------
__global__ void k_deg(const int* __restrict__ dst, int* __restrict__ deg) {
    int e = blockIdx.x*blockDim.x + threadIdx.x;
    if (e < NE) atomicAdd(&deg[dst[e]], 1);
}

__global__ void k_scan1(const int* __restrict__ deg, int* __restrict__ exc, int* __restrict__ sums) {
    __shared__ int buf[2][SCAN_CHUNK];
    int t = threadIdx.x;
    int gi = blockIdx.x*SCAN_CHUNK + t;
    int v = (gi < NN) ? deg[gi] : 0;
    buf[0][t] = v;
    __syncthreads();
    int cur = 0;
    for (int off = 1; off < SCAN_CHUNK; off <<= 1) {
        int nv = buf[cur][t] + ((t >= off) ? buf[cur][t-off] : 0);
        buf[cur^1][t] = nv;
        __syncthreads();
        cur ^= 1;
    }
    if (gi < NN) exc[gi] = buf[cur][t] - v;      // exclusive within chunk
    if (t == SCAN_CHUNK-1) sums[blockIdx.x] = buf[cur][t];
}

__global__ void k_scan2(int* sums, int nb) {
    if (threadIdx.x == 0 && blockIdx.x == 0) {
        int acc = 0;
        for (int i = 0; i < nb; ++i) { int v = sums[i]; sums[i] = acc; acc += v; }
    }
}

__global__ void k_scan3(const int* __restrict__ exc, const int* __restrict__ sums,
                        int* __restrict__ rowptr) {
    int i = blockIdx.x*blockDim.x + threadIdx.x;
    if (i < NN) rowptr[i] = exc[i] + sums[i / SCAN_CHUNK];
    if (i == NN) rowptr[NN] = NE;
}

__global__ void k_scatter(const int* __restrict__ dst, const int* __restrict__ rowptr,
                          int* __restrict__ cnt, int* __restrict__ eid) {
    int e = blockIdx.x*blockDim.x + threadIdx.x;
    if (e < NE) {
        int d = dst[e];
        int pos = atomicAdd(&cnt[d], 1);
        eid[rowptr[d] + pos] = e;
    }
}

// ---------------- tiled fp32 GEMM: C[M,Nc] = A[M,128] * B[128,Nc] (+bias) ----------------
// BM=64, BN=64, BK=64 (2 k-tiles), 256 threads, 4x4 microtile.
template<bool OUT_BF16>
__global__ void k_gemm128(const float* __restrict__ A, const float* __restrict__ B,
                          const float* __restrict__ bias, void* __restrict__ Cout,
                          int M, int Nc) {
    __shared__ float As[64][68];
    __shared__ float Bs[64][64];
    int tid = threadIdx.x;
    int bm = blockIdx.x * 64;
    int bn = blockIdx.y * 64;
    int tx = tid & 15, ty = tid >> 4;
    float acc[4][4] = {};

    for (int kt = 0; kt < 2; ++kt) {
        __syncthreads();
        #pragma unroll
        for (int i = 0; i < 4; ++i) {        // A tile: 64 rows x 64 cols
            int idx = tid + i*256;
            int r = idx >> 4;
            int c4 = (idx & 15) * 4;
            int row = bm + r;
            float4 v = make_float4(0.f,0.f,0.f,0.f);
            if (row < M) v = *(const float4*)(A + (size_t)row*128 + kt*64 + c4);
            *(float4*)&As[r][c4] = v;
        }
        #pragma unroll
        for (int i = 0; i < 4; ++i) {        // B tile: 64 k x 64 cols
            int idx = tid + i*256;
            int kr = idx >> 4;
            int c4 = (idx & 15) * 4;
            float4 v = *(const float4*)(B + (size_t)(kt*64 + kr)*Nc + bn + c4);
            *(float4*)&Bs[kr][c4] = v;
        }
        __syncthreads();
        #pragma unroll
        for (int kk = 0; kk < 64; kk += 4) {
            float4 a4[4], b4[4];
            #pragma unroll
            for (int i = 0; i < 4; ++i) a4[i] = *(const float4*)&As[ty*4 + i][kk];
            #pragma unroll
            for (int j = 0; j < 4; ++j) b4[j] = *(const float4*)&Bs[kk + j][tx*4];
            #pragma unroll
            for (int i = 0; i < 4; ++i) {
                const float* ap = (const float*)&a4[i];
                #pragma unroll
                for (int k = 0; k < 4; ++k) {
                    float av = ap[k];
                    const float* bp = (const float*)&b4[k];
                    acc[i][0] = fmaf(av, bp[0], acc[i][0]);
                    acc[i][1] = fmaf(av, bp[1], acc[i][1]);
                    acc[i][2] = fmaf(av, bp[2], acc[i][2]);
                    acc[i][3] = fmaf(av, bp[3], acc[i][3]);
                }
            }
        }
    }

    int col = bn + tx*4;
    float b0=0.f,b1=0.f,b2=0.f,b3=0.f;
    if (bias) { b0=bias[col]; b1=bias[col+1]; b2=bias[col+2]; b3=bias[col+3]; }
    #pragma unroll
    for (int i = 0; i < 4; ++i) {
        int row = bm + ty*4 + i;
        if (row < M) {
            float r0=acc[i][0]+b0, r1=acc[i][1]+b1, r2=acc[i][2]+b2, r3=acc[i][3]+b3;
            if (OUT_BF16) {
                ushort4 u = make_ushort4(f2bf(r0), f2bf(r1), f2bf(r2), f2bf(r3));
                *(ushort4*)((unsigned short*)Cout + (size_t)row*Nc + col) = u;
            } else {
                *(float4*)((float*)Cout + (size_t)row*Nc + col) = make_float4(r0,r1,r2,r3);
            }
        }
    }
}

// ---------------- edge logits: one wave per edge ----------------
// logits[e,h] = sum_c leaky_relu(xl[src,h,c]+xr[dst,h,c]+eproj[ea,h,c]) * att[h,c]
__global__ void k_edge_logits(const unsigned short* __restrict__ xl,
                              const unsigned short* __restrict__ xr,
                              const float* __restrict__ eproj,
                              const int* __restrict__ srcv, const int* __restrict__ dstv,
                              const int* __restrict__ eattr,
                              const float* __restrict__ att,
                              float* __restrict__ logits) {
    int gid = blockIdx.x*blockDim.x + threadIdx.x;
    int e = gid >> 6;
    if (e >= NE) return;
    int lane = threadIdx.x & 63;
    int s = srcv[e], d = dstv[e], ea = eattr[e];
    const unsigned short* pl = xl + (size_t)s*HC;
    const unsigned short* pr = xr + (size_t)d*HC;
    const float* pe = eproj + (size_t)ea*HC;
    float part[2];
    #pragma unroll
    for (int ch = 0; ch < 2; ++ch) {
        int base = ch*256 + lane*4;          // heads: ch0 -> 0/1, ch1 -> 2/3
        ushort4 a = *(const ushort4*)(pl + base);
        ushort4 b = *(const ushort4*)(pr + base);
        float4 ev = *(const float4*)(pe + base);
        float4 av = *(const float4*)(att + base);
        float sum;
        sum  = lrelu(bf2f(a.x)+bf2f(b.x)+ev.x)*av.x;
        sum += lrelu(bf2f(a.y)+bf2f(b.y)+ev.y)*av.y;
        sum += lrelu(bf2f(a.z)+bf2f(b.z)+ev.z)*av.z;
        sum += lrelu(bf2f(a.w)+bf2f(b.w)+ev.w)*av.w;
        part[ch] = sum;
    }
    #pragma unroll
    for (int m = 16; m >= 1; m >>= 1) {      // reduce within 32-lane halves
        part[0] += __shfl_xor(part[0], m);
        part[1] += __shfl_xor(part[1], m);
    }
    if (lane == 0)       { logits[(size_t)e*4+0] = part[0]; logits[(size_t)e*4+2] = part[1]; }
    else if (lane == 32) { logits[(size_t)e*4+1] = part[0]; logits[(size_t)e*4+3] = part[1]; }
}

// ---------------- per-node softmax + aggregate + epilogue: one wave per node ----------------
__global__ void k_aggregate(const unsigned short* __restrict__ xl,
                            const float* __restrict__ logits,
                            const int* __restrict__ rowptr, const int* __restrict__ eid,
                            const int* __restrict__ srcv,
                            const float* __restrict__ bias,
                            float* __restrict__ h) {
    int gid = blockIdx.x*blockDim.x + threadIdx.x;
    int n = gid >> 6;
    if (n >= NN) return;
    int lane = threadIdx.x & 63;
    int beg = rowptr[n], end = rowptr[n+1];

    float4 mx = make_float4(-INFINITY, -INFINITY, -INFINITY, -INFINITY);
    for (int p = beg; p < end; ++p) {
        float4 lg = *(const float4*)(logits + (size_t)eid[p]*4);
        mx.x = fmaxf(mx.x, lg.x); mx.y = fmaxf(mx.y, lg.y);
        mx.z = fmaxf(mx.z, lg.z); mx.w = fmaxf(mx.w, lg.w);
    }

    float s0=0.f, s1=0.f, s2=0.f, s3=0.f;
    float acc0[4] = {0,0,0,0}, acc1[4] = {0,0,0,0};
    int off = lane*4;
    for (int p = beg; p < end; ++p) {
        int e = eid[p];
        float4 lg = *(const float4*)(logits + (size_t)e*4);
        float a0 = __expf(lg.x - mx.x), a1 = __expf(lg.y - mx.y);
        float a2 = __expf(lg.z - mx.z), a3 = __expf(lg.w - mx.w);
        s0 += a0; s1 += a1; s2 += a2; s3 += a3;
        const unsigned short* px = xl + (size_t)srcv[e]*HC;
        ushort4 v0 = *(const ushort4*)(px + off);
        ushort4 v1 = *(const ushort4*)(px + 256 + off);
        float w0 = (lane < 32) ? a0 : a1;    // chunk0 heads 0/1
        float w1 = (lane < 32) ? a2 : a3;    // chunk1 heads 2/3
        acc0[0] = fmaf(w0, bf2f(v0.x), acc0[0]);
        acc0[1] = fmaf(w0, bf2f(v0.y), acc0[1]);
        acc0[2] = fmaf(w0, bf2f(v0.z), acc0[2]);
        acc0[3] = fmaf(w0, bf2f(v0.w), acc0[3]);
        acc1[0] = fmaf(w1, bf2f(v1.x), acc1[0]);
        acc1[1] = fmaf(w1, bf2f(v1.y), acc1[1]);
        acc1[2] = fmaf(w1, bf2f(v1.z), acc1[2]);
        acc1[3] = fmaf(w1, bf2f(v1.w), acc1[3]);
    }
    float sh0 = ((lane < 32) ? s0 : s1) + 1e-16f;
    float sh1 = ((lane < 32) ? s2 : s3) + 1e-16f;
    float r[4];
    #pragma unroll
    for (int j = 0; j < 4; ++j) {
        r[j] = acc0[j]/sh0 + acc1[j]/sh1;
        r[j] += __shfl_xor(r[j], 32);        // add the other two heads
    }
    if (lane < 32) {
        int c = lane*4;
        float* hp = h + (size_t)n*DD + c;
        float4 hv = *(const float4*)hp;
        float4 o;
        o.x = hv.x + fmaxf(0.f, 0.25f*r[0] + bias[c+0]);
        o.y = hv.y + fmaxf(0.f, 0.25f*r[1] + bias[c+1]);
        o.z = hv.z + fmaxf(0.f, 0.25f*r[2] + bias[c+2]);
        o.w = hv.w + fmaxf(0.f, 0.25f*r[3] + bias[c+3]);
        *(float4*)hp = o;
    }
}

// ---------------- bond head: out[e,j] = concat(h[src],h[dst]) . Wb[:,j] + bb[j] ----------------
__global__ void k_bond(const float* __restrict__ h,
                       const int* __restrict__ srcv, const int* __restrict__ dstv,
                       const float* __restrict__ Wb, const float* __restrict__ bb,
                       float* __restrict__ out) {
    __shared__ float wb[4096];               // 256 x 16
    int tid = threadIdx.x;
    #pragma unroll
    for (int i = 0; i < 4; ++i) {
        int idx = tid + i*256;
        *(float4*)&wb[idx*4] = *(const float4*)(Wb + idx*4);
    }
    __syncthreads();
    int t = blockIdx.x*256 + tid;            // exact grid: NE*16 threads
    int e = t >> 4, j = t & 15;
    const float* hs = h + (size_t)srcv[e]*DD;
    const float* hd = h + (size_t)dstv[e]*DD;
    float acc = bb[j];
    #pragma unroll 8
    for (int k = 0; k < DD; k += 4) {
        float4 a = *(const float4*)(hs + k);
        acc = fmaf(a.x, wb[(k+0)*16 + j], acc);
        acc = fmaf(a.y, wb[(k+1)*16 + j], acc);
        acc = fmaf(a.z, wb[(k+2)*16 + j], acc);
        acc = fmaf(a.w, wb[(k+3)*16 + j], acc);
    }
    #pragma unroll 8
    for (int k = 0; k < DD; k += 4) {
        float4 a = *(const float4*)(hd + k);
        acc = fmaf(a.x, wb[(128+k+0)*16 + j], acc);
        acc = fmaf(a.y, wb[(128+k+1)*16 + j], acc);
        acc = fmaf(a.z, wb[(128+k+2)*16 + j], acc);
        acc = fmaf(a.w, wb[(128+k+3)*16 + j], acc);
    }
    out[t] = acc;
}

// ---------------- host ----------------
extern "C" void kernel_launch(void* const* d_in, const int* in_sizes, int n_in,
                              void* d_out, int out_size, void* d_ws, size_t ws_size,
                              hipStream_t stream) {
    const int*   x        = (const int*)d_in[0];
    const int*   edge_idx = (const int*)d_in[1];
    const int*   eattr    = (const int*)d_in[2];
    const float* atom_emb = (const float*)d_in[3];
    const float* bond_emb = (const float*)d_in[4];
    const float* Wl  = (const float*)d_in[5];
    const float* bl  = (const float*)d_in[6];
    const float* Wr  = (const float*)d_in[7];
    const float* br  = (const float*)d_in[8];
    const float* We  = (const float*)d_in[9];
    const float* att = (const float*)d_in[10];
    const float* bias= (const float*)d_in[11];
    const float* Wa  = (const float*)d_in[12];
    const float* ba  = (const float*)d_in[13];
    const float* Wb  = (const float*)d_in[14];
    const float* bb  = (const float*)d_in[15];

    const int* src = edge_idx;
    const int* dst = edge_idx + NE;

    char* p = (char*)d_ws;
    auto alloc = [&](size_t bytes) -> void* {
        void* r = p; p += (bytes + 255) & ~(size_t)255; return r;
    };
    float*          h      = (float*)alloc((size_t)NN*DD*4);
    unsigned short* xl     = (unsigned short*)alloc((size_t)NN*HC*2);
    unsigned short* xr     = (unsigned short*)alloc((size_t)NN*HC*2);
    float*          eproj  = (float*)alloc((size_t)VBv*HC*4);
    float*          logits = (float*)alloc((size_t)NE*4*4);
    int*            deg    = (int*)alloc((size_t)NN*4);
    int*            exc    = (int*)alloc((size_t)NN*4);
    int*            sums   = (int*)alloc(256*4);
    int*            rowptr = (int*)alloc((size_t)(NN+1)*4);
    int*            cnt    = (int*)alloc((size_t)NN*4);
    int*            eid    = (int*)alloc((size_t)NE*4);

    float* atom_out = (float*)d_out;                      // [NN,128]
    float* bond_out = atom_out + (size_t)NN*VAv;          // [NE,16]

    hipMemsetAsync(deg, 0, (size_t)NN*4, stream);
    hipMemsetAsync(cnt, 0, (size_t)NN*4, stream);

    k_embed<<<7500, 256, 0, stream>>>(x, atom_emb, h);

    // CSR by dst
    int nchunks = (NN + SCAN_CHUNK - 1) / SCAN_CHUNK;     // 118
    k_deg<<<(NE+255)/256, 256, 0, stream>>>(dst, deg);
    k_scan1<<<nchunks, SCAN_CHUNK, 0, stream>>>(deg, exc, sums);
    k_scan2<<<1, 64, 0, stream>>>(sums, nchunks);
    k_scan3<<<(NN+256)/256, 256, 0, stream>>>(exc, sums, rowptr);
    k_scatter<<<(NE+255)/256, 256, 0, stream>>>(dst, rowptr, cnt, eid);

    for (int l = 0; l < NL; ++l) {
        const float* Wl_l = Wl + (size_t)l*DD*HC;
        const float* Wr_l = Wr + (size_t)l*DD*HC;
        const float* We_l = We + (size_t)l*DD*HC;
        const float* bl_l = bl + (size_t)l*HC;
        const float* br_l = br + (size_t)l*HC;
        const float* att_l  = att  + (size_t)l*NH*VAv;    // [4][128]
        const float* bias_l = bias + (size_t)l*DD;

        k_gemm128<false><<<dim3(1, HC/64), 256, 0, stream>>>(bond_emb, We_l, (const float*)nullptr, eproj, VBv, HC);
        k_gemm128<true ><<<dim3((NN+63)/64, HC/64), 256, 0, stream>>>(h, Wl_l, bl_l, xl, NN, HC);
        k_gemm128<true ><<<dim3((NN+63)/64, HC/64), 256, 0, stream>>>(h, Wr_l, br_l, xr, NN, HC);
        k_edge_logits<<<NE/4, 256, 0, stream>>>(xl, xr, eproj, src, dst, eattr, att_l, logits);
        k_aggregate<<<NN/4, 256, 0, stream>>>(xl, logits, rowptr, eid, src, bias_l, h);
    }

    k_gemm128<false><<<dim3((NN+63)/64, VAv/64), 256, 0, stream>>>(h, Wa, ba, atom_out, NN, VAv);
    k_bond<<<NE*16/256, 256, 0, stream>>>(h, src, dst, Wb, bb, bond_out);
}

// Round 2
// 907.658 us; speedup vs baseline: 1.4617x; 1.4617x over previous
//
#include <hip/hip_runtime.h>
#include <hip/hip_bf16.h>
#include <math.h>

#define NN 60000
#define NE 200000
#define DD 128
#define NH 4
#define HC 512   // NH * C
#define NL 3
#define VAv 128
#define VBv 16
#define SCAN_CHUNK 512

typedef __attribute__((ext_vector_type(8))) short bf16x8;
typedef __attribute__((ext_vector_type(4))) float f32x4;

__device__ __forceinline__ float bf2f(unsigned short u){
    union{unsigned int i; float f;} v; v.i = ((unsigned int)u)<<16; return v.f;
}
__device__ __forceinline__ unsigned short f2bf(float f){
    union{float f; unsigned int i;} v; v.f = f;
    unsigned int r = v.i + 0x7fffu + ((v.i>>16)&1u);
    return (unsigned short)(r>>16);
}
__device__ __forceinline__ float lrelu(float v){ return v > 0.f ? v : 0.2f*v; }

#define GLOAD_LDS16(g, l) \
    __builtin_amdgcn_global_load_lds((const __attribute__((address_space(1))) void*)(g), \
                                     (__attribute__((address_space(3))) void*)(l), 16, 0, 0)

// ---------------- embedding gather: h[n,:] = atom_emb[x[n],:] (fp32 + bf16 copies) ----
__global__ void k_embed(const int* __restrict__ x, const float* __restrict__ atom_emb,
                        float* __restrict__ h, unsigned short* __restrict__ hb) {
    int idx = blockIdx.x*blockDim.x + threadIdx.x;   // float4 index
    if (idx >= NN*(DD/4)) return;
    int n = idx >> 5;          // DD/4 == 32
    int c4 = idx & 31;
    int a = x[n];
    float4 v = ((const float4*)(atom_emb + (size_t)a*DD))[c4];
    ((float4*)(h + (size_t)n*DD))[c4] = v;
    ushort4 u = make_ushort4(f2bf(v.x), f2bf(v.y), f2bf(v.z), f2bf(v.w));
    ((ushort4*)(hb + (size_t)n*DD))[c4] = u;
}

// ---------------- weight convert: W[l][128][512] fp32 -> Wt[l][512][128] bf16 --------
__global__ void k_convw(const float* __restrict__ Wl, const float* __restrict__ Wr,
                        unsigned short* __restrict__ Wlt, unsigned short* __restrict__ Wrt) {
    int t = blockIdx.x*256 + threadIdx.x;
    if (t >= NL*DD*HC) return;
    int l = t / (DD*HC);
    int r = t % (DD*HC);
    int n = r / DD;      // 0..511
    int k = r % DD;      // 0..127
    size_t si = (size_t)l*DD*HC + (size_t)k*HC + n;
    Wlt[t] = f2bf(Wl[si]);
    Wrt[t] = f2bf(Wr[si]);
}

// ---------------- CSR build ----------------
__global__ void k_deg(const int* __restrict__ dst, int* __restrict__ deg) {
    int e = blockIdx.x*blockDim.x + threadIdx.x;
    if (e < NE) atomicAdd(&deg[dst[e]], 1);
}

__global__ void k_scan1(const int* __restrict__ deg, int* __restrict__ exc, int* __restrict__ sums) {
    __shared__ int buf[2][SCAN_CHUNK];
    int t = threadIdx.x;
    int gi = blockIdx.x*SCAN_CHUNK + t;
    int v = (gi < NN) ? deg[gi] : 0;
    buf[0][t] = v;
    __syncthreads();
    int cur = 0;
    for (int off = 1; off < SCAN_CHUNK; off <<= 1) {
        int nv = buf[cur][t] + ((t >= off) ? buf[cur][t-off] : 0);
        buf[cur^1][t] = nv;
        __syncthreads();
        cur ^= 1;
    }
    if (gi < NN) exc[gi] = buf[cur][t] - v;
    if (t == SCAN_CHUNK-1) sums[blockIdx.x] = buf[cur][t];
}

__global__ void k_scan2(int* sums, int nb) {
    if (threadIdx.x == 0 && blockIdx.x == 0) {
        int acc = 0;
        for (int i = 0; i < nb; ++i) { int v = sums[i]; sums[i] = acc; acc += v; }
    }
}

__global__ void k_scan3(const int* __restrict__ exc, const int* __restrict__ sums,
                        int* __restrict__ rowptr) {
    int i = blockIdx.x*blockDim.x + threadIdx.x;
    if (i < NN) rowptr[i] = exc[i] + sums[i / SCAN_CHUNK];
    if (i == NN) rowptr[NN] = NE;
}

__global__ void k_scatter(const int* __restrict__ dst, const int* __restrict__ rowptr,
                          int* __restrict__ cnt, int* __restrict__ eid) {
    int e = blockIdx.x*blockDim.x + threadIdx.x;
    if (e < NE) {
        int d = dst[e];
        int pos = atomicAdd(&cnt[d], 1);
        eid[rowptr[d] + pos] = e;
    }
}

// ---------------- MFMA bf16 GEMM: C[M,Nc] = A[M,128] * Bt[Nc,128]^T (+bias) ----------
// A, Bt bf16 row-major (128 cols = 256B rows). 128x128 tile, full K staged once.
// Staging: global_load_lds w=16, source-side XOR swizzle chunk^=(row&7); reads swizzled.
template<bool OUT_BF16>
__global__ __launch_bounds__(256)
void k_gemm_mfma(const unsigned short* __restrict__ A,
                 const unsigned short* __restrict__ Bt,
                 const float* __restrict__ bias, void* __restrict__ Cout,
                 int M, int Nc) {
    __shared__ unsigned short As[128*128];
    __shared__ unsigned short Bs[128*128];
    int tid = threadIdx.x;
    int lane = tid & 63;
    int wave = tid >> 6;
    int bn = blockIdx.x * 128;
    int bm = blockIdx.y * 128;

    #pragma unroll
    for (int it = 0; it < 8; ++it) {
        int slot = it*256 + tid;        // 16B-chunk slot, 2048 total per tile
        int row  = slot >> 4;
        int cph  = slot & 15;
        int clog = cph ^ (row & 7);
        int arow = bm + row; if (arow >= M) arow = M - 1;
        unsigned short* ldst = (unsigned short*)As + (size_t)(it*256 + (tid & ~63))*8;
        GLOAD_LDS16(A + (size_t)arow*128 + clog*8, ldst);
        unsigned short* ldstB = (unsigned short*)Bs + (size_t)(it*256 + (tid & ~63))*8;
        GLOAD_LDS16(Bt + (size_t)(bn + row)*128 + clog*8, ldstB);
    }
    asm volatile("s_waitcnt vmcnt(0)" ::: "memory");
    __syncthreads();

    int wm = (wave >> 1) * 64;
    int wn = (wave & 1) * 64;
    int l15 = lane & 15;
    int l4  = lane >> 4;             // 0..3

    f32x4 acc[4][4];
    #pragma unroll
    for (int i = 0; i < 4; ++i)
        #pragma unroll
        for (int j = 0; j < 4; ++j)
            acc[i][j] = (f32x4){0.f, 0.f, 0.f, 0.f};

    #pragma unroll
    for (int ks = 0; ks < 4; ++ks) {
        bf16x8 af[4], bfr[4];
        int chunk = ks*4 + l4;
        #pragma unroll
        for (int mi = 0; mi < 4; ++mi) {
            int row = wm + mi*16 + l15;
            int cph = chunk ^ (row & 7);
            af[mi] = *(const bf16x8*)(As + row*128 + cph*8);
        }
        #pragma unroll
        for (int ni = 0; ni < 4; ++ni) {
            int row = wn + ni*16 + l15;
            int cph = chunk ^ (row & 7);
            bfr[ni] = *(const bf16x8*)(Bs + row*128 + cph*8);
        }
        #pragma unroll
        for (int mi = 0; mi < 4; ++mi)
            #pragma unroll
            for (int ni = 0; ni < 4; ++ni)
                acc[mi][ni] = __builtin_amdgcn_mfma_f32_16x16x32_bf16(af[mi], bfr[ni], acc[mi][ni], 0, 0, 0);
    }

    #pragma unroll
    for (int mi = 0; mi < 4; ++mi) {
        #pragma unroll
        for (int ni = 0; ni < 4; ++ni) {
            int col = bn + wn + ni*16 + l15;
            float bv = bias ? bias[col] : 0.f;
            #pragma unroll
            for (int r = 0; r < 4; ++r) {
                int row = bm + wm + mi*16 + l4*4 + r;
                if (row < M) {
                    float v = acc[mi][ni][r] + bv;
                    if (OUT_BF16) ((unsigned short*)Cout)[(size_t)row*Nc + col] = f2bf(v);
                    else          ((float*)Cout)[(size_t)row*Nc + col] = v;
                }
            }
        }
    }
}

// ---------------- tiled fp32 GEMM (kept for eproj + Wa head, accuracy) --------------
template<bool OUT_BF16>
__global__ void k_gemm128(const float* __restrict__ A, const float* __restrict__ B,
                          const float* __restrict__ bias, void* __restrict__ Cout,
                          int M, int Nc) {
    __shared__ float As[64][68];
    __shared__ float Bs[64][64];
    int tid = threadIdx.x;
    int bm = blockIdx.x * 64;
    int bn = blockIdx.y * 64;
    int tx = tid & 15, ty = tid >> 4;
    float acc[4][4] = {};

    for (int kt = 0; kt < 2; ++kt) {
        __syncthreads();
        #pragma unroll
        for (int i = 0; i < 4; ++i) {
            int idx = tid + i*256;
            int r = idx >> 4;
            int c4 = (idx & 15) * 4;
            int row = bm + r;
            float4 v = make_float4(0.f,0.f,0.f,0.f);
            if (row < M) v = *(const float4*)(A + (size_t)row*128 + kt*64 + c4);
            *(float4*)&As[r][c4] = v;
        }
        #pragma unroll
        for (int i = 0; i < 4; ++i) {
            int idx = tid + i*256;
            int kr = idx >> 4;
            int c4 = (idx & 15) * 4;
            float4 v = *(const float4*)(B + (size_t)(kt*64 + kr)*Nc + bn + c4);
            *(float4*)&Bs[kr][c4] = v;
        }
        __syncthreads();
        #pragma unroll
        for (int kk = 0; kk < 64; kk += 4) {
            float4 a4[4], b4[4];
            #pragma unroll
            for (int i = 0; i < 4; ++i) a4[i] = *(const float4*)&As[ty*4 + i][kk];
            #pragma unroll
            for (int j = 0; j < 4; ++j) b4[j] = *(const float4*)&Bs[kk + j][tx*4];
            #pragma unroll
            for (int i = 0; i < 4; ++i) {
                const float* ap = (const float*)&a4[i];
                #pragma unroll
                for (int k = 0; k < 4; ++k) {
                    float av = ap[k];
                    const float* bp = (const float*)&b4[k];
                    acc[i][0] = fmaf(av, bp[0], acc[i][0]);
                    acc[i][1] = fmaf(av, bp[1], acc[i][1]);
                    acc[i][2] = fmaf(av, bp[2], acc[i][2]);
                    acc[i][3] = fmaf(av, bp[3], acc[i][3]);
                }
            }
        }
    }

    int col = bn + tx*4;
    float b0=0.f,b1=0.f,b2=0.f,b3=0.f;
    if (bias) { b0=bias[col]; b1=bias[col+1]; b2=bias[col+2]; b3=bias[col+3]; }
    #pragma unroll
    for (int i = 0; i < 4; ++i) {
        int row = bm + ty*4 + i;
        if (row < M) {
            float r0=acc[i][0]+b0, r1=acc[i][1]+b1, r2=acc[i][2]+b2, r3=acc[i][3]+b3;
            if (OUT_BF16) {
                ushort4 u = make_ushort4(f2bf(r0), f2bf(r1), f2bf(r2), f2bf(r3));
                *(ushort4*)((unsigned short*)Cout + (size_t)row*Nc + col) = u;
            } else {
                *(float4*)((float*)Cout + (size_t)row*Nc + col) = make_float4(r0,r1,r2,r3);
            }
        }
    }
}

// ---------------- edge logits: one wave per edge ----------------
__global__ void k_edge_logits(const unsigned short* __restrict__ xl,
                              const unsigned short* __restrict__ xr,
                              const float* __restrict__ eproj,
                              const int* __restrict__ srcv, const int* __restrict__ dstv,
                              const int* __restrict__ eattr,
                              const float* __restrict__ att,
                              float* __restrict__ logits) {
    int gid = blockIdx.x*blockDim.x + threadIdx.x;
    int e = gid >> 6;
    if (e >= NE) return;
    int lane = threadIdx.x & 63;
    int s = srcv[e], d = dstv[e], ea = eattr[e];
    const unsigned short* pl = xl + (size_t)s*HC;
    const unsigned short* pr = xr + (size_t)d*HC;
    const float* pe = eproj + (size_t)ea*HC;
    float part[2];
    #pragma unroll
    for (int ch = 0; ch < 2; ++ch) {
        int base = ch*256 + lane*4;
        ushort4 a = *(const ushort4*)(pl + base);
        ushort4 b = *(const ushort4*)(pr + base);
        float4 ev = *(const float4*)(pe + base);
        float4 av = *(const float4*)(att + base);
        float sum;
        sum  = lrelu(bf2f(a.x)+bf2f(b.x)+ev.x)*av.x;
        sum += lrelu(bf2f(a.y)+bf2f(b.y)+ev.y)*av.y;
        sum += lrelu(bf2f(a.z)+bf2f(b.z)+ev.z)*av.z;
        sum += lrelu(bf2f(a.w)+bf2f(b.w)+ev.w)*av.w;
        part[ch] = sum;
    }
    #pragma unroll
    for (int m = 16; m >= 1; m >>= 1) {
        part[0] += __shfl_xor(part[0], m);
        part[1] += __shfl_xor(part[1], m);
    }
    if (lane == 0)       { logits[(size_t)e*4+0] = part[0]; logits[(size_t)e*4+2] = part[1]; }
    else if (lane == 32) { logits[(size_t)e*4+1] = part[0]; logits[(size_t)e*4+3] = part[1]; }
}

// ---------------- per-node softmax + aggregate + epilogue: one wave per node --------
__global__ void k_aggregate(const unsigned short* __restrict__ xl,
                            const float* __restrict__ logits,
                            const int* __restrict__ rowptr, const int* __restrict__ eid,
                            const int* __restrict__ srcv,
                            const float* __restrict__ bias,
                            float* __restrict__ h, unsigned short* __restrict__ hb) {
    int gid = blockIdx.x*blockDim.x + threadIdx.x;
    int n = gid >> 6;
    if (n >= NN) return;
    int lane = threadIdx.x & 63;
    int beg = rowptr[n], end = rowptr[n+1];

    float4 mx = make_float4(-INFINITY, -INFINITY, -INFINITY, -INFINITY);
    for (int p = beg; p < end; ++p) {
        float4 lg = *(const float4*)(logits + (size_t)eid[p]*4);
        mx.x = fmaxf(mx.x, lg.x); mx.y = fmaxf(mx.y, lg.y);
        mx.z = fmaxf(mx.z, lg.z); mx.w = fmaxf(mx.w, lg.w);
    }

    float s0=0.f, s1=0.f, s2=0.f, s3=0.f;
    float acc0[4] = {0,0,0,0}, acc1[4] = {0,0,0,0};
    int off = lane*4;
    for (int p = beg; p < end; ++p) {
        int e = eid[p];
        float4 lg = *(const float4*)(logits + (size_t)e*4);
        float a0 = __expf(lg.x - mx.x), a1 = __expf(lg.y - mx.y);
        float a2 = __expf(lg.z - mx.z), a3 = __expf(lg.w - mx.w);
        s0 += a0; s1 += a1; s2 += a2; s3 += a3;
        const unsigned short* px = xl + (size_t)srcv[e]*HC;
        ushort4 v0 = *(const ushort4*)(px + off);
        ushort4 v1 = *(const ushort4*)(px + 256 + off);
        float w0 = (lane < 32) ? a0 : a1;
        float w1 = (lane < 32) ? a2 : a3;
        acc0[0] = fmaf(w0, bf2f(v0.x), acc0[0]);
        acc0[1] = fmaf(w0, bf2f(v0.y), acc0[1]);
        acc0[2] = fmaf(w0, bf2f(v0.z), acc0[2]);
        acc0[3] = fmaf(w0, bf2f(v0.w), acc0[3]);
        acc1[0] = fmaf(w1, bf2f(v1.x), acc1[0]);
        acc1[1] = fmaf(w1, bf2f(v1.y), acc1[1]);
        acc1[2] = fmaf(w1, bf2f(v1.z), acc1[2]);
        acc1[3] = fmaf(w1, bf2f(v1.w), acc1[3]);
    }
    float sh0 = ((lane < 32) ? s0 : s1) + 1e-16f;
    float sh1 = ((lane < 32) ? s2 : s3) + 1e-16f;
    float r[4];
    #pragma unroll
    for (int j = 0; j < 4; ++j) {
        r[j] = acc0[j]/sh0 + acc1[j]/sh1;
        r[j] += __shfl_xor(r[j], 32);
    }
    if (lane < 32) {
        int c = lane*4;
        float* hp = h + (size_t)n*DD + c;
        float4 hv = *(const float4*)hp;
        float4 o;
        o.x = hv.x + fmaxf(0.f, 0.25f*r[0] + bias[c+0]);
        o.y = hv.y + fmaxf(0.f, 0.25f*r[1] + bias[c+1]);
        o.z = hv.z + fmaxf(0.f, 0.25f*r[2] + bias[c+2]);
        o.w = hv.w + fmaxf(0.f, 0.25f*r[3] + bias[c+3]);
        *(float4*)hp = o;
        ushort4 u = make_ushort4(f2bf(o.x), f2bf(o.y), f2bf(o.z), f2bf(o.w));
        *(ushort4*)(hb + (size_t)n*DD + c) = u;
    }
}

// ---------------- bond head ----------------
__global__ void k_bond(const float* __restrict__ h,
                       const int* __restrict__ srcv, const int* __restrict__ dstv,
                       const float* __restrict__ Wb, const float* __restrict__ bb,
                       float* __restrict__ out) {
    __shared__ float wb[4096];
    int tid = threadIdx.x;
    #pragma unroll
    for (int i = 0; i < 4; ++i) {
        int idx = tid + i*256;
        *(float4*)&wb[idx*4] = *(const float4*)(Wb + idx*4);
    }
    __syncthreads();
    int t = blockIdx.x*256 + tid;
    int e = t >> 4, j = t & 15;
    const float* hs = h + (size_t)srcv[e]*DD;
    const float* hd = h + (size_t)dstv[e]*DD;
    float acc = bb[j];
    #pragma unroll 8
    for (int k = 0; k < DD; k += 4) {
        float4 a = *(const float4*)(hs + k);
        acc = fmaf(a.x, wb[(k+0)*16 + j], acc);
        acc = fmaf(a.y, wb[(k+1)*16 + j], acc);
        acc = fmaf(a.z, wb[(k+2)*16 + j], acc);
        acc = fmaf(a.w, wb[(k+3)*16 + j], acc);
    }
    #pragma unroll 8
    for (int k = 0; k < DD; k += 4) {
        float4 a = *(const float4*)(hd + k);
        acc = fmaf(a.x, wb[(128+k+0)*16 + j], acc);
        acc = fmaf(a.y, wb[(128+k+1)*16 + j], acc);
        acc = fmaf(a.z, wb[(128+k+2)*16 + j], acc);
        acc = fmaf(a.w, wb[(128+k+3)*16 + j], acc);
    }
    out[t] = acc;
}

// ---------------- host ----------------
extern "C" void kernel_launch(void* const* d_in, const int* in_sizes, int n_in,
                              void* d_out, int out_size, void* d_ws, size_t ws_size,
                              hipStream_t stream) {
    const int*   x        = (const int*)d_in[0];
    const int*   edge_idx = (const int*)d_in[1];
    const int*   eattr    = (const int*)d_in[2];
    const float* atom_emb = (const float*)d_in[3];
    const float* bond_emb = (const float*)d_in[4];
    const float* Wl  = (const float*)d_in[5];
    const float* bl  = (const float*)d_in[6];
    const float* Wr  = (const float*)d_in[7];
    const float* br  = (const float*)d_in[8];
    const float* We  = (const float*)d_in[9];
    const float* att = (const float*)d_in[10];
    const float* bias= (const float*)d_in[11];
    const float* Wa  = (const float*)d_in[12];
    const float* ba  = (const float*)d_in[13];
    const float* Wb  = (const float*)d_in[14];
    const float* bb  = (const float*)d_in[15];

    const int* src = edge_idx;
    const int* dst = edge_idx + NE;

    char* p = (char*)d_ws;
    auto alloc = [&](size_t bytes) -> void* {
        void* r = p; p += (bytes + 255) & ~(size_t)255; return r;
    };
    float*          h      = (float*)alloc((size_t)NN*DD*4);
    unsigned short* hb     = (unsigned short*)alloc((size_t)NN*DD*2);
    unsigned short* xl     = (unsigned short*)alloc((size_t)NN*HC*2);
    unsigned short* xr     = (unsigned short*)alloc((size_t)NN*HC*2);
    unsigned short* Wlt    = (unsigned short*)alloc((size_t)NL*DD*HC*2);
    unsigned short* Wrt    = (unsigned short*)alloc((size_t)NL*DD*HC*2);
    float*          eproj  = (float*)alloc((size_t)VBv*HC*4);
    float*          logits = (float*)alloc((size_t)NE*4*4);
    int*            deg    = (int*)alloc((size_t)NN*4);
    int*            exc    = (int*)alloc((size_t)NN*4);
    int*            sums   = (int*)alloc(256*4);
    int*            rowptr = (int*)alloc((size_t)(NN+1)*4);
    int*            cnt    = (int*)alloc((size_t)NN*4);
    int*            eid    = (int*)alloc((size_t)NE*4);

    float* atom_out = (float*)d_out;                      // [NN,128]
    float* bond_out = atom_out + (size_t)NN*VAv;          // [NE,16]

    hipMemsetAsync(deg, 0, (size_t)NN*4, stream);
    hipMemsetAsync(cnt, 0, (size_t)NN*4, stream);

    k_embed<<<7500, 256, 0, stream>>>(x, atom_emb, h, hb);
    k_convw<<<(NL*DD*HC + 255)/256, 256, 0, stream>>>(Wl, Wr, Wlt, Wrt);

    // CSR by dst
    int nchunks = (NN + SCAN_CHUNK - 1) / SCAN_CHUNK;
    k_deg<<<(NE+255)/256, 256, 0, stream>>>(dst, deg);
    k_scan1<<<nchunks, SCAN_CHUNK, 0, stream>>>(deg, exc, sums);
    k_scan2<<<1, 64, 0, stream>>>(sums, nchunks);
    k_scan3<<<(NN+256)/256, 256, 0, stream>>>(exc, sums, rowptr);
    k_scatter<<<(NE+255)/256, 256, 0, stream>>>(dst, rowptr, cnt, eid);

    int mtiles = (NN + 127) / 128;     // 469
    for (int l = 0; l < NL; ++l) {
        const float* We_l = We + (size_t)l*DD*HC;
        const float* bl_l = bl + (size_t)l*HC;
        const float* br_l = br + (size_t)l*HC;
        const float* att_l  = att  + (size_t)l*NH*VAv;
        const float* bias_l = bias + (size_t)l*DD;
        const unsigned short* Wlt_l = Wlt + (size_t)l*DD*HC;
        const unsigned short* Wrt_l = Wrt + (size_t)l*DD*HC;

        k_gemm128<false><<<dim3(1, HC/64), 256, 0, stream>>>(bond_emb, We_l, (const float*)nullptr, eproj, VBv, HC);
        k_gemm_mfma<true><<<dim3(HC/128, mtiles), 256, 0, stream>>>(hb, Wlt_l, bl_l, xl, NN, HC);
        k_gemm_mfma<true><<<dim3(HC/128, mtiles), 256, 0, stream>>>(hb, Wrt_l, br_l, xr, NN, HC);
        k_edge_logits<<<NE/4, 256, 0, stream>>>(xl, xr, eproj, src, dst, eattr, att_l, logits);
        k_aggregate<<<NN/4, 256, 0, stream>>>(xl, logits, rowptr, eid, src, bias_l, h, hb);
    }

    k_gemm128<false><<<dim3((NN+63)/64, VAv/64), 256, 0, stream>>>(h, Wa, ba, atom_out, NN, VAv);
    k_bond<<<NE*16/256, 256, 0, stream>>>(h, src, dst, Wb, bb, bond_out);
}

// Round 3
// 634.857 us; speedup vs baseline: 2.0897x; 1.4297x over previous
//
#include <hip/hip_runtime.h>
#include <hip/hip_bf16.h>
#include <math.h>

#define NN 60000
#define NE 200000
#define DD 128
#define NH 4
#define HC 512   // NH * C
#define NL 3
#define VAv 128
#define VBv 16
#define SCAN_CHUNK 512

typedef __attribute__((ext_vector_type(8))) short bf16x8;
typedef __attribute__((ext_vector_type(4))) float f32x4;

__device__ __forceinline__ float bf2f(unsigned short u){
    union{unsigned int i; float f;} v; v.i = ((unsigned int)u)<<16; return v.f;
}
__device__ __forceinline__ unsigned short f2bf(float f){
    union{float f; unsigned int i;} v; v.f = f;
    unsigned int r = v.i + 0x7fffu + ((v.i>>16)&1u);
    return (unsigned short)(r>>16);
}
__device__ __forceinline__ float lrelu(float v){ return v > 0.f ? v : 0.2f*v; }

#define GLOAD_LDS16(g, l) \
    __builtin_amdgcn_global_load_lds((const __attribute__((address_space(1))) void*)(g), \
                                     (__attribute__((address_space(3))) void*)(l), 16, 0, 0)

// ---------------- embedding gather: h[n,:] = atom_emb[x[n],:] (fp32 + bf16 copies) ----
__global__ void k_embed(const int* __restrict__ x, const float* __restrict__ atom_emb,
                        float* __restrict__ h, unsigned short* __restrict__ hb) {
    int idx = blockIdx.x*blockDim.x + threadIdx.x;   // float4 index
    if (idx >= NN*(DD/4)) return;
    int n = idx >> 5;          // DD/4 == 32
    int c4 = idx & 31;
    int a = x[n];
    float4 v = ((const float4*)(atom_emb + (size_t)a*DD))[c4];
    ((float4*)(h + (size_t)n*DD))[c4] = v;
    ushort4 u = make_ushort4(f2bf(v.x), f2bf(v.y), f2bf(v.z), f2bf(v.w));
    ((ushort4*)(hb + (size_t)n*DD))[c4] = u;
}

// ---------------- weight convert: W[l][128][512] fp32 -> Wt[l][512][128] bf16 --------
__global__ void k_convw(const float* __restrict__ Wl, const float* __restrict__ Wr,
                        unsigned short* __restrict__ Wlt, unsigned short* __restrict__ Wrt) {
    int t = blockIdx.x*256 + threadIdx.x;
    if (t >= NL*DD*HC) return;
    int l = t / (DD*HC);
    int r = t % (DD*HC);
    int n = r / DD;      // 0..511
    int k = r % DD;      // 0..127
    size_t si = (size_t)l*DD*HC + (size_t)k*HC + n;
    Wlt[t] = f2bf(Wl[si]);
    Wrt[t] = f2bf(Wr[si]);
}

// ---------------- Wa convert: Wa[128][128] fp32 -> Wat[128][128] bf16 transposed -----
__global__ void k_convwa(const float* __restrict__ Wa, unsigned short* __restrict__ Wat) {
    int t = blockIdx.x*256 + threadIdx.x;
    if (t >= DD*VAv) return;
    int n = t / DD;      // out col 0..127
    int k = t % DD;
    Wat[t] = f2bf(Wa[(size_t)k*VAv + n]);
}

// ---------------- eproj (all layers): eprojb[l][v][n] = dot(bond_emb[v], We[l][:,n]) -
__global__ void k_eproj(const float* __restrict__ bond_emb, const float* __restrict__ We,
                        unsigned short* __restrict__ eprojb) {
    int t = blockIdx.x*256 + threadIdx.x;    // 24576 total
    if (t >= NL*VBv*HC) return;
    int n = t & (HC-1);
    int v = (t >> 9) & (VBv-1);
    int l = t >> 13;
    const float* be = bond_emb + (size_t)v*DD;         // wave-uniform -> scalar
    const float* w  = We + (size_t)l*DD*HC + n;
    float acc = 0.f;
    #pragma unroll 8
    for (int k = 0; k < DD; ++k) acc = fmaf(be[k], w[(size_t)k*HC], acc);
    eprojb[t] = f2bf(acc);
}

// ---------------- CSR build ----------------
__global__ void k_deg(const int* __restrict__ dst, int* __restrict__ deg) {
    int e = blockIdx.x*blockDim.x + threadIdx.x;
    if (e < NE) atomicAdd(&deg[dst[e]], 1);
}

__global__ void k_scan1(const int* __restrict__ deg, int* __restrict__ exc, int* __restrict__ sums) {
    __shared__ int buf[2][SCAN_CHUNK];
    int t = threadIdx.x;
    int gi = blockIdx.x*SCAN_CHUNK + t;
    int v = (gi < NN) ? deg[gi] : 0;
    buf[0][t] = v;
    __syncthreads();
    int cur = 0;
    for (int off = 1; off < SCAN_CHUNK; off <<= 1) {
        int nv = buf[cur][t] + ((t >= off) ? buf[cur][t-off] : 0);
        buf[cur^1][t] = nv;
        __syncthreads();
        cur ^= 1;
    }
    if (gi < NN) exc[gi] = buf[cur][t] - v;
    if (t == SCAN_CHUNK-1) sums[blockIdx.x] = buf[cur][t];
}

__global__ void k_scan2(int* sums, int nb) {     // nb <= 128, single block of 128
    __shared__ int buf[2][128];
    int t = threadIdx.x;
    int v = (t < nb) ? sums[t] : 0;
    buf[0][t] = v;
    __syncthreads();
    int cur = 0;
    for (int off = 1; off < 128; off <<= 1) {
        int nv = buf[cur][t] + ((t >= off) ? buf[cur][t-off] : 0);
        buf[cur^1][t] = nv;
        __syncthreads();
        cur ^= 1;
    }
    if (t < nb) sums[t] = buf[cur][t] - v;       // exclusive
}

__global__ void k_scan3(const int* __restrict__ exc, const int* __restrict__ sums,
                        int* __restrict__ rowptr) {
    int i = blockIdx.x*blockDim.x + threadIdx.x;
    if (i < NN) rowptr[i] = exc[i] + sums[i / SCAN_CHUNK];
    if (i == NN) rowptr[NN] = NE;
}

__global__ void k_scatter(const int* __restrict__ dst, const int* __restrict__ rowptr,
                          int* __restrict__ cnt, int* __restrict__ eid) {
    int e = blockIdx.x*blockDim.x + threadIdx.x;
    if (e < NE) {
        int d = dst[e];
        int pos = atomicAdd(&cnt[d], 1);
        eid[rowptr[d] + pos] = e;
    }
}

// ---------------- MFMA bf16 GEMM: C[M,Nc] = A[M,128] * Bt[Nc,128]^T (+bias) ----------
template<bool OUT_BF16>
__global__ __launch_bounds__(256)
void k_gemm_mfma(const unsigned short* __restrict__ A,
                 const unsigned short* __restrict__ Bt,
                 const float* __restrict__ bias, void* __restrict__ Cout,
                 int M, int Nc) {
    __shared__ unsigned short As[128*128];
    __shared__ unsigned short Bs[128*128];
    int tid = threadIdx.x;
    int lane = tid & 63;
    int wave = tid >> 6;
    int bn = blockIdx.x * 128;
    int bm = blockIdx.y * 128;

    #pragma unroll
    for (int it = 0; it < 8; ++it) {
        int slot = it*256 + tid;        // 16B-chunk slot, 2048 total per tile
        int row  = slot >> 4;
        int cph  = slot & 15;
        int clog = cph ^ (row & 7);
        int arow = bm + row; if (arow >= M) arow = M - 1;
        unsigned short* ldst = (unsigned short*)As + (size_t)(it*256 + (tid & ~63))*8;
        GLOAD_LDS16(A + (size_t)arow*128 + clog*8, ldst);
        unsigned short* ldstB = (unsigned short*)Bs + (size_t)(it*256 + (tid & ~63))*8;
        GLOAD_LDS16(Bt + (size_t)(bn + row)*128 + clog*8, ldstB);
    }
    asm volatile("s_waitcnt vmcnt(0)" ::: "memory");
    __syncthreads();

    int wm = (wave >> 1) * 64;
    int wn = (wave & 1) * 64;
    int l15 = lane & 15;
    int l4  = lane >> 4;

    f32x4 acc[4][4];
    #pragma unroll
    for (int i = 0; i < 4; ++i)
        #pragma unroll
        for (int j = 0; j < 4; ++j)
            acc[i][j] = (f32x4){0.f, 0.f, 0.f, 0.f};

    #pragma unroll
    for (int ks = 0; ks < 4; ++ks) {
        bf16x8 af[4], bfr[4];
        int chunk = ks*4 + l4;
        #pragma unroll
        for (int mi = 0; mi < 4; ++mi) {
            int row = wm + mi*16 + l15;
            int cph = chunk ^ (row & 7);
            af[mi] = *(const bf16x8*)(As + row*128 + cph*8);
        }
        #pragma unroll
        for (int ni = 0; ni < 4; ++ni) {
            int row = wn + ni*16 + l15;
            int cph = chunk ^ (row & 7);
            bfr[ni] = *(const bf16x8*)(Bs + row*128 + cph*8);
        }
        #pragma unroll
        for (int mi = 0; mi < 4; ++mi)
            #pragma unroll
            for (int ni = 0; ni < 4; ++ni)
                acc[mi][ni] = __builtin_amdgcn_mfma_f32_16x16x32_bf16(af[mi], bfr[ni], acc[mi][ni], 0, 0, 0);
    }

    #pragma unroll
    for (int mi = 0; mi < 4; ++mi) {
        #pragma unroll
        for (int ni = 0; ni < 4; ++ni) {
            int col = bn + wn + ni*16 + l15;
            float bv = bias ? bias[col] : 0.f;
            #pragma unroll
            for (int r = 0; r < 4; ++r) {
                int row = bm + wm + mi*16 + l4*4 + r;
                if (row < M) {
                    float v = acc[mi][ni][r] + bv;
                    if (OUT_BF16) ((unsigned short*)Cout)[(size_t)row*Nc + col] = f2bf(v);
                    else          ((float*)Cout)[(size_t)row*Nc + col] = v;
                }
            }
        }
    }
}

// ---- fused edge-logits + softmax + aggregate + epilogue: one wave per node ----------
// logits are bounded (|l| ~< 3): softmax computed as exp(l)/sum(exp(l)), no max pass.
__global__ __launch_bounds__(256)
void k_aggregate(const unsigned short* __restrict__ xl,
                 const unsigned short* __restrict__ xr,
                 const unsigned short* __restrict__ eprojb,   // [16][512] bf16, this layer
                 const int* __restrict__ rowptr, const int* __restrict__ eid,
                 const int* __restrict__ srcv, const int* __restrict__ eattr,
                 const float* __restrict__ att,               // [4][128], this layer
                 const float* __restrict__ bias,              // [128], this layer
                 float* __restrict__ h, unsigned short* __restrict__ hb) {
    int gid = blockIdx.x*blockDim.x + threadIdx.x;
    int n = gid >> 6;
    if (n >= NN) return;
    int lane = threadIdx.x & 63;
    int off0 = lane*4, off1 = 256 + lane*4;

    ushort4 xr0u = *(const ushort4*)(xr + (size_t)n*HC + off0);
    ushort4 xr1u = *(const ushort4*)(xr + (size_t)n*HC + off1);
    float xr0[4] = {bf2f(xr0u.x), bf2f(xr0u.y), bf2f(xr0u.z), bf2f(xr0u.w)};
    float xr1[4] = {bf2f(xr1u.x), bf2f(xr1u.y), bf2f(xr1u.z), bf2f(xr1u.w)};
    float4 av0 = *(const float4*)(att + off0);
    float4 av1 = *(const float4*)(att + off1);

    float sum0 = 0.f, sum1 = 0.f;
    float acc0[4] = {0,0,0,0}, acc1[4] = {0,0,0,0};
    int beg = rowptr[n], end = rowptr[n+1];
    for (int p = beg; p < end; ++p) {
        int e = eid[p];
        int s = srcv[e], ea = eattr[e];
        const unsigned short* px = xl + (size_t)s*HC;
        ushort4 a0 = *(const ushort4*)(px + off0);
        ushort4 a1 = *(const ushort4*)(px + off1);
        const unsigned short* pe = eprojb + (size_t)ea*HC;
        ushort4 e0 = *(const ushort4*)(pe + off0);
        ushort4 e1 = *(const ushort4*)(pe + off1);
        float a0f[4] = {bf2f(a0.x), bf2f(a0.y), bf2f(a0.z), bf2f(a0.w)};
        float a1f[4] = {bf2f(a1.x), bf2f(a1.y), bf2f(a1.z), bf2f(a1.w)};
        float p0, p1;
        p0  = lrelu(a0f[0] + xr0[0] + bf2f(e0.x))*av0.x;
        p0 += lrelu(a0f[1] + xr0[1] + bf2f(e0.y))*av0.y;
        p0 += lrelu(a0f[2] + xr0[2] + bf2f(e0.z))*av0.z;
        p0 += lrelu(a0f[3] + xr0[3] + bf2f(e0.w))*av0.w;
        p1  = lrelu(a1f[0] + xr1[0] + bf2f(e1.x))*av1.x;
        p1 += lrelu(a1f[1] + xr1[1] + bf2f(e1.y))*av1.y;
        p1 += lrelu(a1f[2] + xr1[2] + bf2f(e1.z))*av1.z;
        p1 += lrelu(a1f[3] + xr1[3] + bf2f(e1.w))*av1.w;
        #pragma unroll
        for (int m = 16; m >= 1; m >>= 1) {   // reduce within 32-lane halves
            p0 += __shfl_xor(p0, m);
            p1 += __shfl_xor(p1, m);
        }
        float w0 = __expf(p0), w1 = __expf(p1);   // head 0/1 per half (chunk0), 2/3 (chunk1)
        sum0 += w0; sum1 += w1;
        #pragma unroll
        for (int j = 0; j < 4; ++j) {
            acc0[j] = fmaf(w0, a0f[j], acc0[j]);
            acc1[j] = fmaf(w1, a1f[j], acc1[j]);
        }
    }
    float sh0 = sum0 + 1e-16f, sh1 = sum1 + 1e-16f;
    float r[4];
    #pragma unroll
    for (int j = 0; j < 4; ++j) {
        r[j] = acc0[j]/sh0 + acc1[j]/sh1;
        r[j] += __shfl_xor(r[j], 32);             // combine the two head-halves
    }
    if (lane < 32) {
        int c = lane*4;
        float* hp = h + (size_t)n*DD + c;
        float4 hv = *(const float4*)hp;
        float4 o;
        o.x = hv.x + fmaxf(0.f, 0.25f*r[0] + bias[c+0]);
        o.y = hv.y + fmaxf(0.f, 0.25f*r[1] + bias[c+1]);
        o.z = hv.z + fmaxf(0.f, 0.25f*r[2] + bias[c+2]);
        o.w = hv.w + fmaxf(0.f, 0.25f*r[3] + bias[c+3]);
        *(float4*)hp = o;
        ushort4 u = make_ushort4(f2bf(o.x), f2bf(o.y), f2bf(o.z), f2bf(o.w));
        *(ushort4*)(hb + (size_t)n*DD + c) = u;
    }
}

// ---------------- bond head: thread per edge, bf16 gathers, scalar Wb ----------------
__global__ __launch_bounds__(256)
void k_bond(const unsigned short* __restrict__ hb,
            const int* __restrict__ srcv, const int* __restrict__ dstv,
            const float* __restrict__ Wb, const float* __restrict__ bb,
            float* __restrict__ out) {
    int e = blockIdx.x*256 + threadIdx.x;
    if (e >= NE) return;
    int s = srcv[e], d = dstv[e];
    const bf16x8* hs = (const bf16x8*)(hb + (size_t)s*DD);
    const bf16x8* hd = (const bf16x8*)(hb + (size_t)d*DD);
    float acc[16];
    #pragma unroll
    for (int j = 0; j < 16; ++j) acc[j] = bb[j];            // uniform -> scalar
    for (int c = 0; c < 16; ++c) {                          // src half: k = c*8+u
        bf16x8 v = hs[c];
        #pragma unroll
        for (int u = 0; u < 8; ++u) {
            float a = bf2f((unsigned short)v[u]);
            const float* w = Wb + (size_t)(c*8 + u)*16;     // uniform -> scalar
            #pragma unroll
            for (int j = 0; j < 16; ++j) acc[j] = fmaf(a, w[j], acc[j]);
        }
    }
    for (int c = 0; c < 16; ++c) {                          // dst half: k = 128+c*8+u
        bf16x8 v = hd[c];
        #pragma unroll
        for (int u = 0; u < 8; ++u) {
            float a = bf2f((unsigned short)v[u]);
            const float* w = Wb + (size_t)(128 + c*8 + u)*16;
            #pragma unroll
            for (int j = 0; j < 16; ++j) acc[j] = fmaf(a, w[j], acc[j]);
        }
    }
    float4* o = (float4*)(out + (size_t)e*16);
    o[0] = make_float4(acc[0],  acc[1],  acc[2],  acc[3]);
    o[1] = make_float4(acc[4],  acc[5],  acc[6],  acc[7]);
    o[2] = make_float4(acc[8],  acc[9],  acc[10], acc[11]);
    o[3] = make_float4(acc[12], acc[13], acc[14], acc[15]);
}

// ---------------- host ----------------
extern "C" void kernel_launch(void* const* d_in, const int* in_sizes, int n_in,
                              void* d_out, int out_size, void* d_ws, size_t ws_size,
                              hipStream_t stream) {
    const int*   x        = (const int*)d_in[0];
    const int*   edge_idx = (const int*)d_in[1];
    const int*   eattr    = (const int*)d_in[2];
    const float* atom_emb = (const float*)d_in[3];
    const float* bond_emb = (const float*)d_in[4];
    const float* Wl  = (const float*)d_in[5];
    const float* bl  = (const float*)d_in[6];
    const float* Wr  = (const float*)d_in[7];
    const float* br  = (const float*)d_in[8];
    const float* We  = (const float*)d_in[9];
    const float* att = (const float*)d_in[10];
    const float* bias= (const float*)d_in[11];
    const float* Wa  = (const float*)d_in[12];
    const float* ba  = (const float*)d_in[13];
    const float* Wb  = (const float*)d_in[14];
    const float* bb  = (const float*)d_in[15];

    const int* src = edge_idx;
    const int* dst = edge_idx + NE;

    char* p = (char*)d_ws;
    auto alloc = [&](size_t bytes) -> void* {
        void* r = p; p += (bytes + 255) & ~(size_t)255; return r;
    };
    float*          h      = (float*)alloc((size_t)NN*DD*4);
    unsigned short* hb     = (unsigned short*)alloc((size_t)NN*DD*2);
    unsigned short* xl     = (unsigned short*)alloc((size_t)NN*HC*2);
    unsigned short* xr     = (unsigned short*)alloc((size_t)NN*HC*2);
    unsigned short* Wlt    = (unsigned short*)alloc((size_t)NL*DD*HC*2);
    unsigned short* Wrt    = (unsigned short*)alloc((size_t)NL*DD*HC*2);
    unsigned short* Wat    = (unsigned short*)alloc((size_t)DD*VAv*2);
    unsigned short* eprojb = (unsigned short*)alloc((size_t)NL*VBv*HC*2);
    int*            deg    = (int*)alloc((size_t)NN*4);
    int*            exc    = (int*)alloc((size_t)NN*4);
    int*            sums   = (int*)alloc(256*4);
    int*            rowptr = (int*)alloc((size_t)(NN+1)*4);
    int*            cnt    = (int*)alloc((size_t)NN*4);
    int*            eid    = (int*)alloc((size_t)NE*4);

    float* atom_out = (float*)d_out;                      // [NN,128]
    float* bond_out = atom_out + (size_t)NN*VAv;          // [NE,16]

    hipMemsetAsync(deg, 0, (size_t)NN*4, stream);
    hipMemsetAsync(cnt, 0, (size_t)NN*4, stream);

    k_embed<<<7500, 256, 0, stream>>>(x, atom_emb, h, hb);
    k_convw<<<(NL*DD*HC + 255)/256, 256, 0, stream>>>(Wl, Wr, Wlt, Wrt);
    k_convwa<<<(DD*VAv + 255)/256, 256, 0, stream>>>(Wa, Wat);
    k_eproj<<<(NL*VBv*HC + 255)/256, 256, 0, stream>>>(bond_emb, We, eprojb);

    // CSR by dst
    int nchunks = (NN + SCAN_CHUNK - 1) / SCAN_CHUNK;     // 118
    k_deg<<<(NE+255)/256, 256, 0, stream>>>(dst, deg);
    k_scan1<<<nchunks, SCAN_CHUNK, 0, stream>>>(deg, exc, sums);
    k_scan2<<<1, 128, 0, stream>>>(sums, nchunks);
    k_scan3<<<(NN+256)/256, 256, 0, stream>>>(exc, sums, rowptr);
    k_scatter<<<(NE+255)/256, 256, 0, stream>>>(dst, rowptr, cnt, eid);

    int mtiles = (NN + 127) / 128;     // 469
    for (int l = 0; l < NL; ++l) {
        const float* bl_l = bl + (size_t)l*HC;
        const float* br_l = br + (size_t)l*HC;
        const float* att_l  = att  + (size_t)l*NH*VAv;
        const float* bias_l = bias + (size_t)l*DD;
        const unsigned short* Wlt_l = Wlt + (size_t)l*DD*HC;
        const unsigned short* Wrt_l = Wrt + (size_t)l*DD*HC;
        const unsigned short* ep_l  = eprojb + (size_t)l*VBv*HC;

        k_gemm_mfma<true><<<dim3(HC/128, mtiles), 256, 0, stream>>>(hb, Wlt_l, bl_l, xl, NN, HC);
        k_gemm_mfma<true><<<dim3(HC/128, mtiles), 256, 0, stream>>>(hb, Wrt_l, br_l, xr, NN, HC);
        k_aggregate<<<NN/4, 256, 0, stream>>>(xl, xr, ep_l, rowptr, eid, src, eattr,
                                              att_l, bias_l, h, hb);
    }

    k_gemm_mfma<false><<<dim3(VAv/128, mtiles), 256, 0, stream>>>(hb, Wat, ba, atom_out, NN, VAv);
    k_bond<<<(NE+255)/256, 256, 0, stream>>>(hb, src, dst, Wb, bb, bond_out);
}

// Round 4
// 585.164 us; speedup vs baseline: 2.2672x; 1.0849x over previous
//
#include <hip/hip_runtime.h>
#include <hip/hip_bf16.h>
#include <math.h>

#define NN 60000
#define NE 200000
#define DD 128
#define NH 4
#define HC 512   // NH * C
#define NL 3
#define VAv 128
#define VBv 16
#define SCAN_CHUNK 512

typedef __attribute__((ext_vector_type(8))) short bf16x8;
typedef __attribute__((ext_vector_type(4))) float f32x4;

__device__ __forceinline__ float bf2f(unsigned short u){
    union{unsigned int i; float f;} v; v.i = ((unsigned int)u)<<16; return v.f;
}
__device__ __forceinline__ unsigned short f2bf(float f){
    union{float f; unsigned int i;} v; v.f = f;
    unsigned int r = v.i + 0x7fffu + ((v.i>>16)&1u);
    return (unsigned short)(r>>16);
}

#define GLOAD_LDS16(g, l) \
    __builtin_amdgcn_global_load_lds((const __attribute__((address_space(1))) void*)(g), \
                                     (__attribute__((address_space(3))) void*)(l), 16, 0, 0)

// ---------------- embedding gather: h[n,:] = atom_emb[x[n],:] (fp32 + bf16) ----------
__global__ void k_embed(const int* __restrict__ x, const float* __restrict__ atom_emb,
                        float* __restrict__ h, unsigned short* __restrict__ hb) {
    int idx = blockIdx.x*blockDim.x + threadIdx.x;   // float4 index
    if (idx >= NN*(DD/4)) return;
    int n = idx >> 5;
    int c4 = idx & 31;
    int a = x[n];
    float4 v = ((const float4*)(atom_emb + (size_t)a*DD))[c4];
    ((float4*)(h + (size_t)n*DD))[c4] = v;
    ushort4 u = make_ushort4(f2bf(v.x), f2bf(v.y), f2bf(v.z), f2bf(v.w));
    ((ushort4*)(hb + (size_t)n*DD))[c4] = u;
}

// -------- weight convert: [Wl|Wr] -> Wlrt[l][1024][128] bf16 transposed; blr ---------
__global__ void k_convw(const float* __restrict__ Wl, const float* __restrict__ Wr,
                        const float* __restrict__ bl, const float* __restrict__ br,
                        unsigned short* __restrict__ Wlrt, float* __restrict__ blr) {
    int t = blockIdx.x*256 + threadIdx.x;
    if (t < NL*1024*DD) {
        int l = t / (1024*DD);
        int r = t % (1024*DD);
        int n = r / DD;      // 0..1023
        int k = r % DD;
        float v = (n < HC) ? Wl[(size_t)l*DD*HC + (size_t)k*HC + n]
                           : Wr[(size_t)l*DD*HC + (size_t)k*HC + (n - HC)];
        Wlrt[t] = f2bf(v);
    }
    if (t < NL*1024) {
        int l = t / 1024, j = t % 1024;
        blr[t] = (j < HC) ? bl[(size_t)l*HC + j] : br[(size_t)l*HC + (j - HC)];
    }
}

// ---------------- Wa convert: fp32 [128][128] -> bf16 transposed ---------------------
__global__ void k_convwa(const float* __restrict__ Wa, unsigned short* __restrict__ Wat) {
    int t = blockIdx.x*256 + threadIdx.x;
    if (t >= DD*VAv) return;
    int n = t / DD;
    int k = t % DD;
    Wat[t] = f2bf(Wa[(size_t)k*VAv + n]);
}

// ---------------- eproj (all layers, fp32): eprojf[l][v][n] ---------------------------
__global__ void k_eproj(const float* __restrict__ bond_emb, const float* __restrict__ We,
                        float* __restrict__ eprojf) {
    int t = blockIdx.x*256 + threadIdx.x;    // 24576 total
    if (t >= NL*VBv*HC) return;
    int n = t & (HC-1);
    int v = (t >> 9) & (VBv-1);
    int l = t >> 13;
    const float* be = bond_emb + (size_t)v*DD;         // wave-uniform -> scalar
    const float* w  = We + (size_t)l*DD*HC + n;
    float acc = 0.f;
    #pragma unroll 8
    for (int k = 0; k < DD; ++k) acc = fmaf(be[k], w[(size_t)k*HC], acc);
    eprojf[t] = acc;
}

// ---------------- CSR build ----------------
__global__ void k_deg(const int* __restrict__ dst, int* __restrict__ deg) {
    int e = blockIdx.x*blockDim.x + threadIdx.x;
    if (e < NE) atomicAdd(&deg[dst[e]], 1);
}

__global__ void k_scan1(const int* __restrict__ deg, int* __restrict__ exc, int* __restrict__ sums) {
    __shared__ int buf[2][SCAN_CHUNK];
    int t = threadIdx.x;
    int gi = blockIdx.x*SCAN_CHUNK + t;
    int v = (gi < NN) ? deg[gi] : 0;
    buf[0][t] = v;
    __syncthreads();
    int cur = 0;
    for (int off = 1; off < SCAN_CHUNK; off <<= 1) {
        int nv = buf[cur][t] + ((t >= off) ? buf[cur][t-off] : 0);
        buf[cur^1][t] = nv;
        __syncthreads();
        cur ^= 1;
    }
    if (gi < NN) exc[gi] = buf[cur][t] - v;
    if (t == SCAN_CHUNK-1) sums[blockIdx.x] = buf[cur][t];
}

__global__ void k_scan2(int* sums, int nb) {     // nb <= 128
    __shared__ int buf[2][128];
    int t = threadIdx.x;
    int v = (t < nb) ? sums[t] : 0;
    buf[0][t] = v;
    __syncthreads();
    int cur = 0;
    for (int off = 1; off < 128; off <<= 1) {
        int nv = buf[cur][t] + ((t >= off) ? buf[cur][t-off] : 0);
        buf[cur^1][t] = nv;
        __syncthreads();
        cur ^= 1;
    }
    if (t < nb) sums[t] = buf[cur][t] - v;       // exclusive
}

__global__ void k_scan3(const int* __restrict__ exc, const int* __restrict__ sums,
                        int* __restrict__ rowptr) {
    int i = blockIdx.x*blockDim.x + threadIdx.x;
    if (i < NN) rowptr[i] = exc[i] + sums[i / SCAN_CHUNK];
    if (i == NN) rowptr[NN] = NE;
}

// scatter: store src | (eattr<<16) sorted by dst  (src < 65536, eattr < 16)
__global__ void k_scatter(const int* __restrict__ srcv, const int* __restrict__ dst,
                          const int* __restrict__ eattr, const int* __restrict__ rowptr,
                          int* __restrict__ cnt, int* __restrict__ packed) {
    int e = blockIdx.x*blockDim.x + threadIdx.x;
    if (e < NE) {
        int d = dst[e];
        int pos = atomicAdd(&cnt[d], 1);
        packed[rowptr[d] + pos] = srcv[e] | (eattr[e] << 16);
    }
}

// ---------------- MFMA bf16 GEMM: C[M,Nc] = A[M,128] * Bt[Nc,128]^T (+bias) ----------
template<bool OUT_BF16>
__global__ __launch_bounds__(256)
void k_gemm_mfma(const unsigned short* __restrict__ A,
                 const unsigned short* __restrict__ Bt,
                 const float* __restrict__ bias, void* __restrict__ Cout,
                 int M, int Nc) {
    __shared__ unsigned short As[128*128];
    __shared__ unsigned short Bs[128*128];
    int tid = threadIdx.x;
    int lane = tid & 63;
    int wave = tid >> 6;
    int bn = blockIdx.x * 128;
    int bm = blockIdx.y * 128;

    #pragma unroll
    for (int it = 0; it < 8; ++it) {
        int slot = it*256 + tid;
        int row  = slot >> 4;
        int cph  = slot & 15;
        int clog = cph ^ (row & 7);
        int arow = bm + row; if (arow >= M) arow = M - 1;
        unsigned short* ldst = (unsigned short*)As + (size_t)(it*256 + (tid & ~63))*8;
        GLOAD_LDS16(A + (size_t)arow*128 + clog*8, ldst);
        unsigned short* ldstB = (unsigned short*)Bs + (size_t)(it*256 + (tid & ~63))*8;
        GLOAD_LDS16(Bt + (size_t)(bn + row)*128 + clog*8, ldstB);
    }
    asm volatile("s_waitcnt vmcnt(0)" ::: "memory");
    __syncthreads();

    int wm = (wave >> 1) * 64;
    int wn = (wave & 1) * 64;
    int l15 = lane & 15;
    int l4  = lane >> 4;

    f32x4 acc[4][4];
    #pragma unroll
    for (int i = 0; i < 4; ++i)
        #pragma unroll
        for (int j = 0; j < 4; ++j)
            acc[i][j] = (f32x4){0.f, 0.f, 0.f, 0.f};

    #pragma unroll
    for (int ks = 0; ks < 4; ++ks) {
        bf16x8 af[4], bfr[4];
        int chunk = ks*4 + l4;
        #pragma unroll
        for (int mi = 0; mi < 4; ++mi) {
            int row = wm + mi*16 + l15;
            int cph = chunk ^ (row & 7);
            af[mi] = *(const bf16x8*)(As + row*128 + cph*8);
        }
        #pragma unroll
        for (int ni = 0; ni < 4; ++ni) {
            int row = wn + ni*16 + l15;
            int cph = chunk ^ (row & 7);
            bfr[ni] = *(const bf16x8*)(Bs + row*128 + cph*8);
        }
        #pragma unroll
        for (int mi = 0; mi < 4; ++mi)
            #pragma unroll
            for (int ni = 0; ni < 4; ++ni)
                acc[mi][ni] = __builtin_amdgcn_mfma_f32_16x16x32_bf16(af[mi], bfr[ni], acc[mi][ni], 0, 0, 0);
    }

    #pragma unroll
    for (int mi = 0; mi < 4; ++mi) {
        #pragma unroll
        for (int ni = 0; ni < 4; ++ni) {
            int col = bn + wn + ni*16 + l15;
            float bv = bias ? bias[col] : 0.f;
            #pragma unroll
            for (int r = 0; r < 4; ++r) {
                int row = bm + wm + mi*16 + l4*4 + r;
                if (row < M) {
                    float v = acc[mi][ni][r] + bv;
                    if (OUT_BF16) ((unsigned short*)Cout)[(size_t)row*Nc + col] = f2bf(v);
                    else          ((float*)Cout)[(size_t)row*Nc + col] = v;
                }
            }
        }
    }
}

// ---- fused edge-logits + softmax + aggregate + epilogue ----------------------------
// 8 waves/block, one node per wave. Lane l: head h = l>>4, channels (l&15)*8..+8.
// xlr row layout: [xl 512 | xr 512] bf16.
__global__ __launch_bounds__(512)
void k_aggregate(const unsigned short* __restrict__ xlr,
                 const float* __restrict__ eprojf,   // [16][512] fp32, this layer
                 const int* __restrict__ rowptr, const int* __restrict__ packed,
                 const float* __restrict__ att,      // [4][128], this layer
                 const float* __restrict__ bias,     // [128], this layer
                 float* __restrict__ h, unsigned short* __restrict__ hb) {
    __shared__ float eps[VBv*HC];                    // 32 KB
    {
        const float4* s4 = (const float4*)eprojf;
        float4* d4 = (float4*)eps;
        int t = threadIdx.x;
        #pragma unroll
        for (int i = 0; i < 4; ++i) d4[t + i*512] = s4[t + i*512];
    }
    __syncthreads();

    int wave = threadIdx.x >> 6;
    int lane = threadIdx.x & 63;
    int n = blockIdx.x*8 + wave;                     // 60000/8 = 7500 exact
    int loff = lane*8;                               // = h*128 + (l&15)*8

    float xrf[8], attf[8];
    {
        bf16x8 xv = *(const bf16x8*)(xlr + (size_t)n*1024 + 512 + loff);
        #pragma unroll
        for (int u = 0; u < 8; ++u) xrf[u] = bf2f((unsigned short)xv[u]);
        float4 a0 = *(const float4*)(att + loff);
        float4 a1 = *(const float4*)(att + loff + 4);
        attf[0]=a0.x; attf[1]=a0.y; attf[2]=a0.z; attf[3]=a0.w;
        attf[4]=a1.x; attf[5]=a1.y; attf[6]=a1.z; attf[7]=a1.w;
    }

    float acc[8] = {0,0,0,0,0,0,0,0};
    float wsum = 0.f;
    int beg = rowptr[n], end = rowptr[n+1];

    int p = beg;
    for (; p + 2 <= end; p += 2) {                   // 2 edges in flight
        int pk0 = packed[p], pk1 = packed[p+1];
        int s0 = pk0 & 0xFFFF, ea0 = pk0 >> 16;
        int s1 = pk1 & 0xFFFF, ea1 = pk1 >> 16;
        bf16x8 v0 = *(const bf16x8*)(xlr + (size_t)s0*1024 + loff);
        bf16x8 v1 = *(const bf16x8*)(xlr + (size_t)s1*1024 + loff);
        const float* ep0 = eps + ea0*HC + loff;
        const float* ep1 = eps + ea1*HC + loff;
        float4 e00 = *(const float4*)ep0, e01 = *(const float4*)(ep0+4);
        float4 e10 = *(const float4*)ep1, e11 = *(const float4*)(ep1+4);
        float xf0[8], xf1[8], epa[8], epb[8];
        epa[0]=e00.x; epa[1]=e00.y; epa[2]=e00.z; epa[3]=e00.w;
        epa[4]=e01.x; epa[5]=e01.y; epa[6]=e01.z; epa[7]=e01.w;
        epb[0]=e10.x; epb[1]=e10.y; epb[2]=e10.z; epb[3]=e10.w;
        epb[4]=e11.x; epb[5]=e11.y; epb[6]=e11.z; epb[7]=e11.w;
        float p0 = 0.f, p1 = 0.f;
        #pragma unroll
        for (int u = 0; u < 8; ++u) {
            xf0[u] = bf2f((unsigned short)v0[u]);
            xf1[u] = bf2f((unsigned short)v1[u]);
            float z0 = xf0[u] + xrf[u] + epa[u];
            float z1 = xf1[u] + xrf[u] + epb[u];
            p0 = fmaf(fmaxf(z0, 0.2f*z0), attf[u], p0);
            p1 = fmaf(fmaxf(z1, 0.2f*z1), attf[u], p1);
        }
        p0 += __shfl_xor(p0, 1); p1 += __shfl_xor(p1, 1);
        p0 += __shfl_xor(p0, 2); p1 += __shfl_xor(p1, 2);
        p0 += __shfl_xor(p0, 4); p1 += __shfl_xor(p1, 4);
        p0 += __shfl_xor(p0, 8); p1 += __shfl_xor(p1, 8);
        float w0 = __expf(p0), w1 = __expf(p1);
        wsum += w0 + w1;
        #pragma unroll
        for (int u = 0; u < 8; ++u) {
            acc[u] = fmaf(w0, xf0[u], acc[u]);
            acc[u] = fmaf(w1, xf1[u], acc[u]);
        }
    }
    if (p < end) {                                   // tail edge
        int pk0 = packed[p];
        int s0 = pk0 & 0xFFFF, ea0 = pk0 >> 16;
        bf16x8 v0 = *(const bf16x8*)(xlr + (size_t)s0*1024 + loff);
        const float* ep0 = eps + ea0*HC + loff;
        float4 e00 = *(const float4*)ep0, e01 = *(const float4*)(ep0+4);
        float epa[8];
        epa[0]=e00.x; epa[1]=e00.y; epa[2]=e00.z; epa[3]=e00.w;
        epa[4]=e01.x; epa[5]=e01.y; epa[6]=e01.z; epa[7]=e01.w;
        float xf0[8];
        float p0 = 0.f;
        #pragma unroll
        for (int u = 0; u < 8; ++u) {
            xf0[u] = bf2f((unsigned short)v0[u]);
            float z0 = xf0[u] + xrf[u] + epa[u];
            p0 = fmaf(fmaxf(z0, 0.2f*z0), attf[u], p0);
        }
        p0 += __shfl_xor(p0, 1);
        p0 += __shfl_xor(p0, 2);
        p0 += __shfl_xor(p0, 4);
        p0 += __shfl_xor(p0, 8);
        float w0 = __expf(p0);
        wsum += w0;
        #pragma unroll
        for (int u = 0; u < 8; ++u) acc[u] = fmaf(w0, xf0[u], acc[u]);
    }

    float inv = __builtin_amdgcn_rcpf(wsum + 1e-16f);
    float rr[8];
    #pragma unroll
    for (int u = 0; u < 8; ++u) rr[u] = acc[u] * inv;
    #pragma unroll
    for (int u = 0; u < 8; ++u) rr[u] += __shfl_xor(rr[u], 16);
    #pragma unroll
    for (int u = 0; u < 8; ++u) rr[u] += __shfl_xor(rr[u], 32);

    if (lane < 16) {
        int c = lane*8;
        float* hp = h + (size_t)n*DD + c;
        float4 h0 = *(const float4*)hp;
        float4 h1 = *(const float4*)(hp + 4);
        float4 b0 = *(const float4*)(bias + c);
        float4 b1 = *(const float4*)(bias + c + 4);
        float o[8];
        o[0] = h0.x + fmaxf(0.f, fmaf(0.25f, rr[0], b0.x));
        o[1] = h0.y + fmaxf(0.f, fmaf(0.25f, rr[1], b0.y));
        o[2] = h0.z + fmaxf(0.f, fmaf(0.25f, rr[2], b0.z));
        o[3] = h0.w + fmaxf(0.f, fmaf(0.25f, rr[3], b0.w));
        o[4] = h1.x + fmaxf(0.f, fmaf(0.25f, rr[4], b1.x));
        o[5] = h1.y + fmaxf(0.f, fmaf(0.25f, rr[5], b1.y));
        o[6] = h1.z + fmaxf(0.f, fmaf(0.25f, rr[6], b1.z));
        o[7] = h1.w + fmaxf(0.f, fmaf(0.25f, rr[7], b1.w));
        *(float4*)hp       = make_float4(o[0], o[1], o[2], o[3]);
        *(float4*)(hp + 4) = make_float4(o[4], o[5], o[6], o[7]);
        ushort4 u0 = make_ushort4(f2bf(o[0]), f2bf(o[1]), f2bf(o[2]), f2bf(o[3]));
        ushort4 u1 = make_ushort4(f2bf(o[4]), f2bf(o[5]), f2bf(o[6]), f2bf(o[7]));
        unsigned short* hbp = hb + (size_t)n*DD + c;
        *(ushort4*)hbp       = u0;
        *(ushort4*)(hbp + 4) = u1;
    }
}

// ---------------- bond head: thread per edge, bf16 gathers, scalar Wb ----------------
__global__ __launch_bounds__(256)
void k_bond(const unsigned short* __restrict__ hb,
            const int* __restrict__ srcv, const int* __restrict__ dstv,
            const float* __restrict__ Wb, const float* __restrict__ bb,
            float* __restrict__ out) {
    int e = blockIdx.x*256 + threadIdx.x;
    if (e >= NE) return;
    int s = srcv[e], d = dstv[e];
    const bf16x8* hs = (const bf16x8*)(hb + (size_t)s*DD);
    const bf16x8* hd = (const bf16x8*)(hb + (size_t)d*DD);
    float acc[16];
    #pragma unroll
    for (int j = 0; j < 16; ++j) acc[j] = bb[j];
    for (int c = 0; c < 16; ++c) {
        bf16x8 v = hs[c];
        #pragma unroll
        for (int u = 0; u < 8; ++u) {
            float a = bf2f((unsigned short)v[u]);
            const float* w = Wb + (size_t)(c*8 + u)*16;
            #pragma unroll
            for (int j = 0; j < 16; ++j) acc[j] = fmaf(a, w[j], acc[j]);
        }
    }
    for (int c = 0; c < 16; ++c) {
        bf16x8 v = hd[c];
        #pragma unroll
        for (int u = 0; u < 8; ++u) {
            float a = bf2f((unsigned short)v[u]);
            const float* w = Wb + (size_t)(128 + c*8 + u)*16;
            #pragma unroll
            for (int j = 0; j < 16; ++j) acc[j] = fmaf(a, w[j], acc[j]);
        }
    }
    float4* o = (float4*)(out + (size_t)e*16);
    o[0] = make_float4(acc[0],  acc[1],  acc[2],  acc[3]);
    o[1] = make_float4(acc[4],  acc[5],  acc[6],  acc[7]);
    o[2] = make_float4(acc[8],  acc[9],  acc[10], acc[11]);
    o[3] = make_float4(acc[12], acc[13], acc[14], acc[15]);
}

// ---------------- host ----------------
extern "C" void kernel_launch(void* const* d_in, const int* in_sizes, int n_in,
                              void* d_out, int out_size, void* d_ws, size_t ws_size,
                              hipStream_t stream) {
    const int*   x        = (const int*)d_in[0];
    const int*   edge_idx = (const int*)d_in[1];
    const int*   eattr    = (const int*)d_in[2];
    const float* atom_emb = (const float*)d_in[3];
    const float* bond_emb = (const float*)d_in[4];
    const float* Wl  = (const float*)d_in[5];
    const float* bl  = (const float*)d_in[6];
    const float* Wr  = (const float*)d_in[7];
    const float* br  = (const float*)d_in[8];
    const float* We  = (const float*)d_in[9];
    const float* att = (const float*)d_in[10];
    const float* bias= (const float*)d_in[11];
    const float* Wa  = (const float*)d_in[12];
    const float* ba  = (const float*)d_in[13];
    const float* Wb  = (const float*)d_in[14];
    const float* bb  = (const float*)d_in[15];

    const int* src = edge_idx;
    const int* dst = edge_idx + NE;

    char* p = (char*)d_ws;
    auto alloc = [&](size_t bytes) -> void* {
        void* r = p; p += (bytes + 255) & ~(size_t)255; return r;
    };
    float*          h      = (float*)alloc((size_t)NN*DD*4);
    unsigned short* hb     = (unsigned short*)alloc((size_t)NN*DD*2);
    unsigned short* xlr    = (unsigned short*)alloc((size_t)NN*1024*2);
    unsigned short* Wlrt   = (unsigned short*)alloc((size_t)NL*1024*DD*2);
    float*          blr    = (float*)alloc((size_t)NL*1024*4);
    unsigned short* Wat    = (unsigned short*)alloc((size_t)DD*VAv*2);
    float*          eprojf = (float*)alloc((size_t)NL*VBv*HC*4);
    int*            deg    = (int*)alloc((size_t)NN*4);
    int*            exc    = (int*)alloc((size_t)NN*4);
    int*            sums   = (int*)alloc(256*4);
    int*            rowptr = (int*)alloc((size_t)(NN+1)*4);
    int*            cnt    = (int*)alloc((size_t)NN*4);
    int*            packed = (int*)alloc((size_t)NE*4);

    float* atom_out = (float*)d_out;                      // [NN,128]
    float* bond_out = atom_out + (size_t)NN*VAv;          // [NE,16]

    hipMemsetAsync(deg, 0, (size_t)NN*4, stream);
    hipMemsetAsync(cnt, 0, (size_t)NN*4, stream);

    k_embed<<<7500, 256, 0, stream>>>(x, atom_emb, h, hb);
    k_convw<<<(NL*1024*DD + 255)/256, 256, 0, stream>>>(Wl, Wr, bl, br, Wlrt, blr);
    k_convwa<<<(DD*VAv + 255)/256, 256, 0, stream>>>(Wa, Wat);
    k_eproj<<<(NL*VBv*HC + 255)/256, 256, 0, stream>>>(bond_emb, We, eprojf);

    // CSR by dst
    int nchunks = (NN + SCAN_CHUNK - 1) / SCAN_CHUNK;     // 118
    k_deg<<<(NE+255)/256, 256, 0, stream>>>(dst, deg);
    k_scan1<<<nchunks, SCAN_CHUNK, 0, stream>>>(deg, exc, sums);
    k_scan2<<<1, 128, 0, stream>>>(sums, nchunks);
    k_scan3<<<(NN+256)/256, 256, 0, stream>>>(exc, sums, rowptr);
    k_scatter<<<(NE+255)/256, 256, 0, stream>>>(src, dst, eattr, rowptr, cnt, packed);

    int mtiles = (NN + 127) / 128;     // 469
    for (int l = 0; l < NL; ++l) {
        const float* att_l  = att  + (size_t)l*NH*VAv;
        const float* bias_l = bias + (size_t)l*DD;
        const unsigned short* Wlrt_l = Wlrt + (size_t)l*1024*DD;
        const float* blr_l = blr + (size_t)l*1024;
        const float* ep_l  = eprojf + (size_t)l*VBv*HC;

        k_gemm_mfma<true><<<dim3(1024/128, mtiles), 256, 0, stream>>>(hb, Wlrt_l, blr_l, xlr, NN, 1024);
        k_aggregate<<<NN/8, 512, 0, stream>>>(xlr, ep_l, rowptr, packed, att_l, bias_l, h, hb);
    }

    k_gemm_mfma<false><<<dim3(VAv/128, mtiles), 256, 0, stream>>>(hb, Wat, ba, atom_out, NN, VAv);
    k_bond<<<(NE+255)/256, 256, 0, stream>>>(hb, src, dst, Wb, bb, bond_out);
}